// Round 1
// 113.347 us; speedup vs baseline: 1.0152x; 1.0152x over previous
//
#include <hip/hip_runtime.h>

constexpr int   BATCH = 2;
constexpr int   NPTS  = 524288;            // P = 2^19
constexpr int   BINS  = 2048;              // BATCH * 32 * 32 tiles
constexpr int   CAP   = 768;               // per-bin capacity (mean 512, +11 sigma)
constexpr float BETA  = 4.71238898038469f; // 1.5*pi
constexpr float PI_F  = 3.14159265358979f;

typedef float v2f __attribute__((ext_vector_type(2)));

// LDS pad-16: breaks power-of-2 strides (butterflies + digit-rev readout)
#define PIDX(i) ((i) + ((i) >> 4))

// ---------------- workspace layout ----------------
// g1 : 16 MB @ 0          (row-FFT output, dim1 in padded/shifted time order)
// gT : 16 MB @ 16 MB      (g1 transposed: gT[c][r])
// gF : aliases g1 @ 0     (final grid, TRANSPOSED: gF[c][f1]; g1 dead by then)
// gcnt : 8 KB @ 32 MB     (zeroed by block 0 of rows_and_bin)
// perm : BINS x CAP float4 records {x.x, x.y, gid, -} = 25.2 MB
constexpr size_t G1_OFF   = 0;
constexpr size_t GT_OFF   = (size_t)16 << 20;
constexpr size_t GF_OFF   = 0;
constexpr size_t GCNT_OFF = (size_t)32 << 20;
constexpr size_t PERM_OFF = GCNT_OFF + 8192;

// i0(x) for x >= 3.75 (Numerical Recipes asymptotic, rel err ~1e-7)
__device__ __forceinline__ float i0f_large(float x) {
    float t = 3.75f / x;
    float p =  0.00392377f;
    p = p * t + -0.01647633f;
    p = p * t +  0.02635537f;
    p = p * t + -0.02057706f;
    p = p * t +  0.00916281f;
    p = p * t + -0.00157565f;
    p = p * t +  0.00225319f;
    p = p * t +  0.01328592f;
    p = p * t +  0.39894228f;
    return __expf(x) * rsqrtf(x) * p;
}

__device__ __forceinline__ int tile_of(v2f xv, int b) {
    int c1 = ((int)floorf(xv.x * 1024.0f)) & 1023;
    int c2 = ((int)floorf(xv.y * 1024.0f)) & 1023;
    return (b << 10) + ((c1 >> 5) << 5) + (c2 >> 5);
}

// cmul via packed f32: t stores (c, s, -s, c); a*w = a.x*(c,s) + a.y*(-s,c)
__device__ __forceinline__ v2f cmul4(v2f a, float4 t) {
    v2f lo = {t.x, t.y}, hi = {t.z, t.w};
    return a.x * lo + a.y * hi;            // v_pk_mul + v_pk_fma
}
__device__ __forceinline__ v2f irot(v2f b) { return (v2f){-b.y, b.x}; }  // i*b

// Natural freq f -> storage position after radix-4 DIF (5 digit-reversed
// base-4 digits) = bit-reverse then swap bits within pairs. Involution.
__device__ __forceinline__ int digitrev4_10(int f) {
    unsigned r = __brev((unsigned)f) >> 22;
    return (int)(((r & 0x2AAu) >> 1) | ((r & 0x155u) << 1));
}

// Stage-concatenated radix-4 twiddles, 1023 float4 (c,s,-s,c):
// stage offsets: q=256 @0, q=64 @768, q=16 @960, q=4 @1008, q=1 @1020.
__device__ __forceinline__ void build_tw4(float4* T, int tid, int nthreads) {
    int off = 0, q = 256, sig = 1;
    #pragma unroll
    for (int st = 0; st < 5; ++st) {
        for (int m = tid; m < 3 * q; m += nthreads) {
            int sec = 0, j = m;
            if (j >= q) { sec++; j -= q; }
            if (j >= q) { sec++; j -= q; }
            float ang = (-2.0f * PI_F / 1024.0f) * (float)((sec + 1) * j * sig);
            float sw, cw;
            __sincosf(ang, &sw, &cw);
            T[off + m] = make_float4(cw, sw, -sw, cw);
        }
        off += 3 * q; q >>= 2; sig <<= 2;
    }
}

// One radix-4 DIF butterfly at index bt for stage with quarter-stride q.
__device__ __forceinline__ void bfly4(v2f* s, const float4* T,
                                      int bt, int q, int off) {
    int j    = bt & (q - 1);
    int base = ((bt - j) << 2) + j;        // (bt/q)*4q + j
    int p0 = PIDX(base), p1 = PIDX(base + q);
    int p2 = PIDX(base + 2 * q), p3 = PIDX(base + 3 * q);
    v2f a0 = s[p0], a1 = s[p1], a2 = s[p2], a3 = s[p3];
    v2f t0 = a0 + a2, t1 = a0 - a2, t2 = a1 + a3, t3 = a1 - a3;
    v2f r3 = irot(t3);
    s[p0] = t0 + t2;
    s[p1] = cmul4(t1 - r3, T[off + j]);
    s[p2] = cmul4(t0 - t2, T[off + q + j]);
    s[p3] = cmul4(t1 + r3, T[off + 2 * q + j]);
}

// ---------------- fused: row FFTs (blocks 0..1023) + binning (1024..1279) ----
// Block 0 additionally zeroes gcnt via device-scope atomics at t~0 (bin
// blocks do >=2us of loads+LDS histogram before touching gcnt).
__global__ __launch_bounds__(256) void rows_and_bin(const v2f* __restrict__ fh,
                                                    v2f* __restrict__ g,
                                                    const v2f* __restrict__ x,
                                                    int* __restrict__ gcnt,
                                                    float4* __restrict__ perm) {
    // fft path: s = 1088 v2f (8704 B, 16-aligned), T = 1023 float4 (16368 B)
    __shared__ __align__(16) char smem[25072];
    int tid = threadIdx.x;

    if (blockIdx.x < 1024) {
        if (blockIdx.x == 0) {
            #pragma unroll
            for (int i = 0; i < 8; ++i)
                atomicExch(&gcnt[tid * 8 + i], 0);
        }
        // ---- row FFT fused with deconvolution (radix-4) ----
        v2f*    s = (v2f*)smem;                  // 1087 used
        float4* T = (float4*)(smem + 8704);      // 1023
        int blk = blockIdx.x & 511;              // 0..511
        int b   = blockIdx.x >> 9;
        int row = (blk < 256) ? blk : blk + 512; // {0..255, 768..1023}
        int a1  = (row + 256) & 1023;            // fh row index, 0..511

        build_tw4(T, tid, 256);

        float k1 = (float)(a1 - 256);
        float w1 = (2.0f * PI_F / 1024.0f) * k1;
        float c1 = i0f_large(4.0f * sqrtf(BETA * BETA - w1 * w1));

        const v2f* fr = fh + ((long)b << 18) + ((long)a1 << 9);

        float w2a = (2.0f * PI_F / 1024.0f) * (float)tid;
        float c2a = i0f_large(4.0f * sqrtf(BETA * BETA - w2a * w2a));
        float w2b = (2.0f * PI_F / 1024.0f) * (float)(tid - 256);
        float c2b = i0f_large(4.0f * sqrtf(BETA * BETA - w2b * w2b));

        v2f A = fr[tid + 256] * (1.0f / (c1 * c2a));   // idx tid
        v2f B = fr[tid]       * (1.0f / (c1 * c2b));   // idx tid+768

        __syncthreads();                          // T ready

        // stage q=256 in regs: {A,0,0,B} -> A+B, (A+iB)w1, (A-B)w2, (A-iB)w3
        v2f rB = irot(B);
        s[PIDX(tid)]       = A + B;
        s[PIDX(tid + 256)] = cmul4(A + rB, T[tid]);
        s[PIDX(tid + 512)] = cmul4(A - B,  T[256 + tid]);
        s[PIDX(tid + 768)] = cmul4(A - rB, T[512 + tid]);

        int off = 768, q = 64;                    // stages q=64,16,4,1 in LDS
        #pragma unroll
        for (int st = 0; st < 4; ++st) {
            __syncthreads();
            bfly4(s, T, tid, q, off);
            off += 3 * q; q >>= 2;
        }
        __syncthreads();

        v2f* base = g + ((long)b << 20) + ((long)row << 10);
        #pragma unroll
        for (int i = 0; i < 4; ++i) {
            int idx = tid + (i << 8);
            base[idx] = s[PIDX(digitrev4_10(idx))];
        }
    } else {
        // ---- binning: 4096 points per block, fat records {x, gid} ----
        int* h = (int*)smem;                     // 2048 ints
        int bblk = blockIdx.x - 1024;            // 0..255
        for (int i = tid; i < BINS; i += 256) h[i] = 0;
        __syncthreads();

        int base = bblk * 4096;
        int tile[16];
        v2f pv[16];
        #pragma unroll
        for (int i = 0; i < 16; ++i) {
            int gid = base + tid + i * 256;
            pv[i]   = x[gid];
            tile[i] = tile_of(pv[i], gid >> 19);
            atomicAdd(&h[tile[i]], 1);
        }
        __syncthreads();

        #pragma unroll
        for (int j = 0; j < 8; ++j) {
            int bi = tid + j * 256;
            int c  = h[bi];
            h[bi]  = c ? atomicAdd(&gcnt[bi], c) : 0;
        }
        __syncthreads();

        #pragma unroll
        for (int i = 0; i < 16; ++i) {
            int gid = base + tid + i * 256;
            int pos = atomicAdd(&h[tile[i]], 1);
            perm[tile[i] * CAP + pos] =
                make_float4(pv[i].x, pv[i].y, __int_as_float(gid), 0.0f);
        }
    }
}

// ---------------- 64x64 tiled transpose of the 512 USED rows --------------
// g1 rows {0..255, 768..1023} -> gT[c][r] (same positions along r).
// Both directions: 512 B contiguous per wave. LDS [64][65] pad.
__global__ __launch_bounds__(256) void transpose_g(const v2f* __restrict__ g1,
                                                   v2f* __restrict__ gT) {
    __shared__ v2f tile[64][65];
    int bid = blockIdx.x;              // 0..255
    int b   = bid >> 7;                // batch
    int t7  = bid & 127;               // rgrp(8) x cgrp(16)
    int rg  = t7 >> 4;                 // 0..7
    int cg  = t7 & 15;                 // 0..15
    int r0  = ((rg < 4) ? rg : rg + 8) << 6;   // {0,64,128,192,768,832,896,960}
    int c0  = cg << 6;
    const v2f* src = g1 + ((long)b << 20);
    v2f*       dst = gT + ((long)b << 20);
    int lw = threadIdx.x >> 6;         // wave 0..3
    int ll = threadIdx.x & 63;         // lane

    #pragma unroll
    for (int k = 0; k < 16; ++k) {
        int r = lw + (k << 2);         // 0..63
        tile[r][ll] = src[((long)(r0 + r) << 10) + c0 + ll];
    }
    __syncthreads();
    #pragma unroll
    for (int k = 0; k < 16; ++k) {
        int c = lw + (k << 2);         // 0..63
        dst[((long)(c0 + c) << 10) + r0 + ll] = tile[ll][c];
    }
}

// ---------------- column FFTs as row FFTs over gT (K1-style) --------------
// One block per (column c, batch b): 256 threads, 4 elems each, stages
// q=256 in regs ({A,0,0,B}) + q=64,16,4,1 in LDS, natural-order contiguous
// write via digit-reversed LDS readout. Output gF = g^T (gF[c][f1]).
__global__ __launch_bounds__(256) void fft_cols2(const v2f* __restrict__ gT,
                                                 v2f* __restrict__ gF) {
    __shared__ __align__(16) char smem[25072];
    v2f*    s = (v2f*)smem;                  // 1087 used
    float4* T = (float4*)(smem + 8704);      // 1023
    int tid = threadIdx.x;
    int c   = blockIdx.x;                    // 0..1023
    int b   = blockIdx.y;

    build_tw4(T, tid, 256);

    const v2f* row = gT + ((long)b << 20) + ((long)c << 10);
    v2f A = row[tid];                        // positions 0..255
    v2f B = row[tid + 768];                  // positions 768..1023

    __syncthreads();                         // T ready

    v2f rB = irot(B);
    s[PIDX(tid)]       = A + B;
    s[PIDX(tid + 256)] = cmul4(A + rB, T[tid]);
    s[PIDX(tid + 512)] = cmul4(A - B,  T[256 + tid]);
    s[PIDX(tid + 768)] = cmul4(A - rB, T[512 + tid]);

    int off = 768, q = 64;                   // stages q=64,16,4,1 in LDS
    #pragma unroll
    for (int st = 0; st < 4; ++st) {
        __syncthreads();
        bfly4(s, T, tid, q, off);
        off += 3 * q; q >>= 2;
    }
    __syncthreads();

    v2f* o = gF + ((long)b << 20) + ((long)c << 10);
    #pragma unroll
    for (int i = 0; i < 4; ++i) {
        int idx = tid + (i << 8);
        o[idx] = s[PIDX(digitrev4_10(idx))];
    }
}

// ---------------- binned gather, 6 taps/dim ----------------
// gF is TRANSPOSED (gF[c][r]): patch is dim2-major, taps swap loop roles.
// Weights via transcendentals (trans pipe overlaps LDS waits; LDS tables
// regressed in an earlier round). Points from fat perm records. Patch 37x37.
__global__ __launch_bounds__(256) void gather_binned(const v2f* __restrict__ gF,
                                                     const int* __restrict__ gcnt,
                                                     const float4* __restrict__ perm,
                                                     v2f* __restrict__ out) {
    __shared__ v2f patch[37 * 37];             // 10.9 KB
    int tb = blockIdx.x;           // 0..2047
    int b  = tb >> 10;
    int tt = tb & 1023;
    int tR = tt >> 5, tC = tt & 31;            // tR: dim1, tC: dim2
    int R0 = (tR << 5) - 2, C0 = (tC << 5) - 2;
    const v2f* gb = gF + ((long)b << 20);

    // patch[ccoff*37 + rroff] = gF[gc][gr]; contiguous in rroff (gr)
    for (int p = threadIdx.x; p < 37 * 37; p += 256) {
        int pa = p / 37, pb = p - pa * 37;     // pa: dim2 offset, pb: dim1
        int gc = (C0 + pa) & 1023, gr = (R0 + pb) & 1023;
        patch[p] = gb[(gc << 10) + gr];
    }
    __syncthreads();

    int cnt = gcnt[tb];
    if (cnt > CAP) cnt = CAP;
    int off0 = tb * CAP;
    for (int i = (int)threadIdx.x; i < cnt; i += 256) {
        float4 rec = perm[off0 + i];
        int gid = __float_as_int(rec.z);

        float w1[6], w2[6];
        int rr0, cc0;
        {
            float xs = rec.x * 1024.0f;
            float fl = floorf(xs);
            float fr = xs - fl;
            rr0 = (((int)fl) & 1023) - (tR << 5);     // 0..31  (dim1)
            #pragma unroll
            for (int k = 0; k < 6; ++k) {
                float tv = fr - (float)(k - 2);       // |tv| < 3 -> u2 > 7
                float u2 = 16.0f - tv * tv;
                float ir = rsqrtf(u2);                // 1/u
                float z  = BETA * u2 * ir;            // beta*u in [12.5,18.9]
                w1[k] = __expf(z) * 0.159154943f * ir;   // sinh(z)/(pi*u)
            }
        }
        {
            float xs = rec.y * 1024.0f;
            float fl = floorf(xs);
            float fr = xs - fl;
            cc0 = (((int)fl) & 1023) - (tC << 5);     // 0..31  (dim2)
            #pragma unroll
            for (int k = 0; k < 6; ++k) {
                float tv = fr - (float)(k - 2);
                float u2 = 16.0f - tv * tv;
                float ir = rsqrtf(u2);
                float z  = BETA * u2 * ir;
                w2[k] = __expf(z) * 0.159154943f * ir;
            }
        }

        v2f acc = {0.0f, 0.0f};
        #pragma unroll
        for (int jj = 0; jj < 6; ++jj) {              // dim2 (patch-major)
            int pbase = (cc0 + jj) * 37 + rr0;
            float wj = w2[jj];
            #pragma unroll
            for (int ii = 0; ii < 6; ++ii)            // dim1 (contiguous)
                acc += (wj * w1[ii]) * patch[pbase + ii];   // v_pk_fma_f32
        }
        out[gid] = acc;
    }
}

extern "C" void kernel_launch(void* const* d_in, const int* in_sizes, int n_in,
                              void* d_out, int out_size, void* d_ws, size_t ws_size,
                              hipStream_t stream) {
    const v2f* x  = (const v2f*)d_in[0];
    const v2f* fh = (const v2f*)d_in[1];
    char* ws = (char*)d_ws;
    v2f*    g1   = (v2f*)(ws + G1_OFF);
    v2f*    gT   = (v2f*)(ws + GT_OFF);
    v2f*    gF   = (v2f*)(ws + GF_OFF);     // aliases g1 (dead after transpose)
    int*    gcnt = (int*)(ws + GCNT_OFF);
    float4* perm = (float4*)(ws + PERM_OFF);

    rows_and_bin <<<dim3(1280),        dim3(256), 0, stream>>>(fh, g1, x, gcnt, perm);
    transpose_g  <<<dim3(256),         dim3(256), 0, stream>>>(g1, gT);
    fft_cols2    <<<dim3(1024, BATCH), dim3(256), 0, stream>>>(gT, gF);
    gather_binned<<<dim3(BINS),        dim3(256), 0, stream>>>(gF, gcnt, perm, (v2f*)d_out);
}